// Round 11
// baseline (304.110 us; speedup 1.0000x reference)
//
#include <hip/hip_runtime.h>
#include <hip/hip_bf16.h>
#include <cstdint>

#define BF16 __hip_bfloat16

typedef __attribute__((ext_vector_type(8))) short bhalf8;   // 8 bf16 (4 VGPRs)
typedef __attribute__((ext_vector_type(4))) float floatx4;  // 4 fp32 acc

#define MFMA16(a, b, c) __builtin_amdgcn_mfma_f32_16x16x32_bf16((a), (b), (c), 0, 0, 0)

#define MASKV (-30000.0f)
#define QSCALE 0.18033688011112042f  // 0.125 * log2(e); folded into Q

// global -> LDS direct copy, 16 B per lane (dwordx4). Dest is wave-uniform
// base + lane*16 (linear); source address is per-lane (pre-swizzled).
#define GLOAD_LDS16(g, l)                                   \
  __builtin_amdgcn_global_load_lds(                         \
      (const __attribute__((address_space(1))) void*)(g),   \
      (__attribute__((address_space(3))) void*)(l), 16, 0, 0)

__device__ __forceinline__ bhalf8 cvt8(const float* p) {
  const float4 f0 = *(const float4*)p;
  const float4 f1 = *(const float4*)(p + 4);
  union { bhalf8 v; ushort u[8]; } r;
  const float t[8] = {f0.x, f0.y, f0.z, f0.w, f1.x, f1.y, f1.z, f1.w};
#pragma unroll
  for (int i = 0; i < 8; ++i) {
    BF16 h = __float2bfloat16(t[i]);
    r.u[i] = *(const ushort*)&h;
  }
  return r.v;
}

// ---------------------------------------------------------------------------
// Bulk f32 -> bf16 convert, 8 elems/thread.
// ---------------------------------------------------------------------------
__global__ void cvt_f32_bf16(const float* __restrict__ in, BF16* __restrict__ out) {
  const size_t i = ((size_t)blockIdx.x * 256 + threadIdx.x) * 8;
  *(bhalf8*)(out + i) = cvt8(in + i);
}

// ---------------------------------------------------------------------------
// Transpose+convert (R x C) f32 -> (C x R) bf16. Block (32,8), LDS 32x33 pad.
// ---------------------------------------------------------------------------
__global__ void transpose_cvt(const float* __restrict__ in, ushort* __restrict__ out,
                              int R, int C) {
  __shared__ ushort t[32][33];
  const int c0 = blockIdx.x * 32, r0 = blockIdx.y * 32;
  const int tx = threadIdx.x, ty = threadIdx.y;
#pragma unroll
  for (int j = 0; j < 32; j += 8) {
    BF16 h = __float2bfloat16(in[(size_t)(r0 + ty + j) * C + c0 + tx]);
    t[ty + j][tx] = *(const ushort*)&h;
  }
  __syncthreads();
#pragma unroll
  for (int j = 0; j < 32; j += 8)
    out[(size_t)(c0 + ty + j) * R + r0 + tx] = t[tx][ty + j];
}

// ---------------------------------------------------------------------------
// OLD-STYLE GEMM (kept for the FC projection; N=1024 grid too small for the
// 256-tile kernel). C = A*Bt^T + bias, 128x128 tile, BK=64, 4 waves.
// ---------------------------------------------------------------------------
template <int MODE>
__global__ __launch_bounds__(256, 2) void gemm_bt(
    const BF16* __restrict__ A, const BF16* __restrict__ Bt, const float* __restrict__ bias,
    void* __restrict__ C0v, BF16* __restrict__ C1, BF16* __restrict__ C2,
    int Md, int Nd, int Kd) {
  __shared__ __align__(16) BF16 As[128 * 64];
  __shared__ __align__(16) BF16 Bs[128 * 64];

  const int tid = threadIdx.x;
  const int w = tid >> 6, lane = tid & 63;
  const int lm = lane & 15, quad = lane >> 4;
  const int wm = (w >> 1) * 64, wn = (w & 1) * 64;

  const int lin = blockIdx.y * gridDim.x + blockIdx.x;
  const int per8 = (gridDim.x * gridDim.y) >> 3;
  const int swz = (lin & 7) * per8 + (lin >> 3);
  const int tile_m = (swz / gridDim.x) * 128, tile_n = (swz % gridDim.x) * 128;

  floatx4 acc[4][4];
#pragma unroll
  for (int i = 0; i < 4; ++i)
#pragma unroll
    for (int j = 0; j < 4; ++j) acc[i][j] = (floatx4){0.f, 0.f, 0.f, 0.f};

  int srow[4], sgs[4], sslot[4];
#pragma unroll
  for (int j = 0; j < 4; ++j) {
    const int slot = (j * 4 + w) * 64 + lane;
    sslot[j] = slot;
    srow[j] = slot >> 3;
    sgs[j] = ((slot & 7) - (slot >> 3)) & 7;
  }

  bhalf8 va[4], vb[4], nva[4], nvb[4];
#pragma unroll
  for (int j = 0; j < 4; ++j) {
    va[j] = *(const bhalf8*)(A + (size_t)(tile_m + srow[j]) * Kd + sgs[j] * 8);
    vb[j] = *(const bhalf8*)(Bt + (size_t)(tile_n + srow[j]) * Kd + sgs[j] * 8);
  }

  for (int k0 = 0; k0 < Kd; k0 += 64) {
    __syncthreads();
#pragma unroll
    for (int j = 0; j < 4; ++j) {
      *(bhalf8*)(As + sslot[j] * 8) = va[j];
      *(bhalf8*)(Bs + sslot[j] * 8) = vb[j];
    }
    __syncthreads();

    if (k0 + 64 < Kd) {
      const int k1 = k0 + 64;
#pragma unroll
      for (int j = 0; j < 4; ++j) {
        nva[j] = *(const bhalf8*)(A + (size_t)(tile_m + srow[j]) * Kd + k1 + sgs[j] * 8);
        nvb[j] = *(const bhalf8*)(Bt + (size_t)(tile_n + srow[j]) * Kd + k1 + sgs[j] * 8);
      }
    }

#pragma unroll
    for (int s = 0; s < 2; ++s) {
      bhalf8 af[4], bfr[4];
#pragma unroll
      for (int mt = 0; mt < 4; ++mt) {
        const int r = wm + mt * 16 + lm;
        const int g = ((s * 4 + quad) + r) & 7;
        af[mt] = *(const bhalf8*)(As + r * 64 + g * 8);
      }
#pragma unroll
      for (int nt = 0; nt < 4; ++nt) {
        const int r = wn + nt * 16 + lm;
        const int g = ((s * 4 + quad) + r) & 7;
        bfr[nt] = *(const bhalf8*)(Bs + r * 64 + g * 8);
      }
#pragma unroll
      for (int mt = 0; mt < 4; ++mt)
#pragma unroll
        for (int nt = 0; nt < 4; ++nt)
          acc[mt][nt] = MFMA16(af[mt], bfr[nt], acc[mt][nt]);
    }
#pragma unroll
    for (int j = 0; j < 4; ++j) { va[j] = nva[j]; vb[j] = nvb[j]; }
  }

#pragma unroll
  for (int nt = 0; nt < 4; ++nt) {
    const int n = tile_n + wn + nt * 16 + lm;
    const float bv = bias[n];
#pragma unroll
    for (int mt = 0; mt < 4; ++mt) {
      const int m0 = tile_m + wm + mt * 16 + quad * 4;
      floatx4 v = acc[mt][nt];
      if (MODE == 0) {
        float* C0f = (float*)C0v;
#pragma unroll
        for (int r = 0; r < 4; ++r)
          C0f[(size_t)(m0 + r) * Nd + n] = v[r] + bv;
      } else {
        const int which = n >> 10;
        const int h = (n >> 6) & 15;
        const int d = n & 63;
        if (which == 2) {
          const int b = m0 >> 11, s0 = m0 & 2047;
          union { ushort4 u4; ushort u[4]; } pk;
#pragma unroll
          for (int r = 0; r < 4; ++r) {
            BF16 hv = __float2bfloat16(v[r] + bv);
            pk.u[r] = *(const ushort*)&hv;
          }
          *(ushort4*)(C2 + ((size_t)((b * 16 + h) * 64 + d)) * 2048 + s0) = pk.u4;
        } else {
          BF16* dst = (which == 0) ? (BF16*)C0v : C1;
          const float sc = (which == 0) ? QSCALE : 1.0f;
#pragma unroll
          for (int r = 0; r < 4; ++r) {
            const int m = m0 + r, b = m >> 11, si = m & 2047;
            dst[((size_t)(b * 16 + h) * 2048 + si) * 64 + d] =
                __float2bfloat16((v[r] + bv) * sc);
          }
        }
      }
    }
  }
}

// ---------------------------------------------------------------------------
// R11: QKV GEMM, 256x256 tile, BK=32, 8 waves, 3-buffer LDS ring, counted
// vmcnt. R10 proved the structure (bank-conflict 0, correct, one barrier per
// 32 MFMA) but spilled: (512,2) implies a 128-VGPR cap while the live set is
// ~190, AND the 96 KB LDS already caps occupancy at 1 block/CU — the bound
// demanded registers for an occupancy the LDS forbids. VGPR_Count=100 +
// WRITE_SIZE 84 MB (~34 MB scratch) was the signature.
// FIX: __launch_bounds__(512, 1) -> 256-VGPR cap. Occupancy unchanged
// (LDS-capped), spills gone. Everything else identical to R10.
// ---------------------------------------------------------------------------
__global__ __launch_bounds__(512, 1) void gemm_qkv256(
    const BF16* __restrict__ A, const BF16* __restrict__ Bt, const float* __restrict__ bias,
    BF16* __restrict__ Qo, BF16* __restrict__ Ko, BF16* __restrict__ Vo, int Kd) {
  __shared__ __align__(16) BF16 As[3][256 * 32];  // 48 KB
  __shared__ __align__(16) BF16 Bs[3][256 * 32];  // 48 KB

  const int tid = threadIdx.x;
  const int w = tid >> 6, lane = tid & 63;
  const int lm = lane & 15, quad = lane >> 4;
  const int wm = w >> 2, wn = w & 3;  // 2 x 4 wave grid; wave owns 128x64 of C

  // XCD-bijective swizzle (grid 12x32 = 384 = 8*48)
  const int lin = blockIdx.y * gridDim.x + blockIdx.x;
  const int per8 = (gridDim.x * gridDim.y) >> 3;
  const int swz = (lin & 7) * per8 + (lin >> 3);
  const int tile_m = (swz / gridDim.x) * 256, tile_n = (swz % gridDim.x) * 256;

  const int NT = Kd >> 5;  // BK=32 K-tiles

  // staging decode: linear dest slot = j*512 + tid (16B units);
  // slot -> row = slot>>2, g = slot&3; stored kgroup kg = (g - (row>>1)) & 3
  int srow[2], skg[2];
#pragma unroll
  for (int j = 0; j < 2; ++j) {
    const int slot = j * 512 + tid;
    srow[j] = slot >> 2;
    skg[j] = ((slot & 3) - ((slot >> 3) & 3)) & 3;
  }
  const int dst0 = w * 64;  // wave-uniform dest slot base (+ j*512)

  floatx4 acc[8][4];
#pragma unroll
  for (int mt = 0; mt < 8; ++mt)
#pragma unroll
    for (int nt = 0; nt < 4; ++nt) acc[mt][nt] = (floatx4){0.f, 0.f, 0.f, 0.f};

  // prologue: stage tiles 0 and 1 into ring slots 0 and 1
#pragma unroll
  for (int t = 0; t < 2; ++t) {
#pragma unroll
    for (int j = 0; j < 2; ++j) {
      GLOAD_LDS16(A + (size_t)(tile_m + srow[j]) * Kd + t * 32 + skg[j] * 8,
                  As[t] + (j * 512 + dst0) * 8);
      GLOAD_LDS16(Bt + (size_t)(tile_n + srow[j]) * Kd + t * 32 + skg[j] * 8,
                  Bs[t] + (j * 512 + dst0) * 8);
    }
  }

  int bc = 0, bs = 2;  // bc = t%3 (compute), bs = (t+2)%3 (stage)
  for (int t = 0; t < NT; ++t) {
    __builtin_amdgcn_sched_barrier(0);  // pin: nothing crosses the boundary
    __builtin_amdgcn_s_barrier();       // raw barrier — no vmcnt drain
    if (t + 1 < NT) {
      asm volatile("s_waitcnt vmcnt(4)" ::: "memory");  // tile t landed; t+1 may fly
    } else {
      asm volatile("s_waitcnt vmcnt(0)" ::: "memory");  // last tile: flush
    }

    if (t + 2 < NT) {  // stage tile t+2 into ring slot bs == (t-1)%3
#pragma unroll
      for (int j = 0; j < 2; ++j) {
        GLOAD_LDS16(A + (size_t)(tile_m + srow[j]) * Kd + (t + 2) * 32 + skg[j] * 8,
                    As[bs] + (j * 512 + dst0) * 8);
        GLOAD_LDS16(Bt + (size_t)(tile_n + srow[j]) * Kd + (t + 2) * 32 + skg[j] * 8,
                    Bs[bs] + (j * 512 + dst0) * 8);
      }
    }

    // fragments (inverse swizzle on read): row r, kgroup quad at
    // group g = (quad + (r>>1)) & 3
    bhalf8 af[8], bfv[4];
#pragma unroll
    for (int mt = 0; mt < 8; ++mt) {
      const int r = wm * 128 + mt * 16 + lm;
      const int g = (quad + ((r >> 1) & 3)) & 3;
      af[mt] = *(const bhalf8*)(As[bc] + r * 32 + g * 8);
    }
#pragma unroll
    for (int nt = 0; nt < 4; ++nt) {
      const int r = wn * 64 + nt * 16 + lm;
      const int g = (quad + ((r >> 1) & 3)) & 3;
      bfv[nt] = *(const bhalf8*)(Bs[bc] + r * 32 + g * 8);
    }

    __builtin_amdgcn_s_setprio(1);
#pragma unroll
    for (int mt = 0; mt < 8; ++mt)
#pragma unroll
      for (int nt = 0; nt < 4; ++nt)
        acc[mt][nt] = MFMA16(af[mt], bfv[nt], acc[mt][nt]);
    __builtin_amdgcn_s_setprio(0);

    bc = (bc == 2) ? 0 : bc + 1;
    bs = (bs == 2) ? 0 : bs + 1;
  }

  // epilogue: QKV scatter. C layout: col(n)=lm, row(m)=quad*4+reg.
#pragma unroll
  for (int nt = 0; nt < 4; ++nt) {
    const int n = tile_n + wn * 64 + nt * 16 + lm;
    const float bv = bias[n];
    const int which = n >> 10;
    const int h = (n >> 6) & 15;
    const int d = n & 63;
#pragma unroll
    for (int mt = 0; mt < 8; ++mt) {
      const int m0 = tile_m + wm * 128 + mt * 16 + quad * 4;
      floatx4 v = acc[mt][nt];
      if (which == 2) {
        // V^T: 4 regs = 4 consecutive s at fixed d -> one 8 B store
        const int b = m0 >> 11, s0 = m0 & 2047;
        union { ushort4 u4; ushort u[4]; } pk;
#pragma unroll
        for (int r = 0; r < 4; ++r) {
          BF16 hv = __float2bfloat16(v[r] + bv);
          pk.u[r] = *(const ushort*)&hv;
        }
        *(ushort4*)(Vo + ((size_t)((b * 16 + h) * 64 + d)) * 2048 + s0) = pk.u4;
      } else {
        BF16* dst = (which == 0) ? Qo : Ko;
        const float sc = (which == 0) ? QSCALE : 1.0f;  // fold softmax scale into Q
#pragma unroll
        for (int r = 0; r < 4; ++r) {
          const int m = m0 + r, b = m >> 11, si = m & 2047;
          dst[((size_t)(b * 16 + h) * 2048 + si) * 64 + d] =
              __float2bfloat16((v[r] + bv) * sc);
        }
      }
    }
  }
}

// ---------------------------------------------------------------------------
// Causal flash attention — R9 version kept verbatim (97.6 us, best measured):
// MFMA row-sum for l, pairwise max tree, lagged PV, defer-max, chunk
// rotation, XCD-bijective grid, (256,2)/116-VGPR no-spill envelope.
// ---------------------------------------------------------------------------
__global__ __launch_bounds__(256, 2) void flash_attn(
    const BF16* __restrict__ Q, const BF16* __restrict__ Kmat,
    const BF16* __restrict__ VT, BF16* __restrict__ O) {
  __shared__ __align__(16) BF16 Ps[4][4][16 * 64];  // [wave][set] = 32 KB

  const int tid = threadIdx.x;
  const int w = tid >> 6, lane = tid & 63;
  const int lm = lane & 15, quad = lane >> 4;

  const int bid = blockIdx.x;
  const int xcd = bid & 7;
  const int li = bid >> 3;
  const int bh = xcd * 8 + (li >> 3);
  const int x = li & 7;

  const int sel = (w + x) & 3;
  const int qt = (sel == 0) ? x : (sel == 1) ? (15 - x) : (sel == 2) ? (16 + x) : (31 - x);
  const int qb0 = qt * 64;
  const size_t bh_off = (size_t)bh * (2048 * 64);

  union { bhalf8 v; ushort u[8]; } onesu;
#pragma unroll
  for (int i = 0; i < 8; ++i) onesu.u[i] = 0x3F80;  // bf16 1.0
  const bhalf8 ones8 = onesu.v;

  bhalf8 aq[4][2];
#pragma unroll
  for (int s2 = 0; s2 < 4; ++s2) {
    const BF16* qp = Q + bh_off + (size_t)(qb0 + s2 * 16 + lm) * 64 + quad * 8;
    aq[s2][0] = *(const bhalf8*)qp;
    aq[s2][1] = *(const bhalf8*)(qp + 32);
  }

  floatx4 oacc[4][4];
  float m_i[4], l_i[4];
#pragma unroll
  for (int s2 = 0; s2 < 4; ++s2) {
    m_i[s2] = MASKV;
    l_i[s2] = 0.f;
#pragma unroll
    for (int i = 0; i < 4; ++i) oacc[s2][i] = (floatx4){0.f, 0.f, 0.f, 0.f};
  }

  for (int kt = 0; kt <= qt; ++kt) {
    const int k0 = kt * 64;

    bhalf8 ak[4][2], av[4][2];
#pragma unroll
    for (int nt = 0; nt < 4; ++nt) {
      const BF16* kp = Kmat + bh_off + (size_t)(k0 + nt * 16 + lm) * 64 + quad * 8;
      ak[nt][0] = *(const bhalf8*)kp;
      ak[nt][1] = *(const bhalf8*)(kp + 32);
      const BF16* vp = VT + bh_off + (size_t)(nt * 16 + lm) * 2048 + k0 + quad * 8;
      av[nt][0] = *(const bhalf8*)vp;
      av[nt][1] = *(const bhalf8*)(vp + 32);
    }

#pragma unroll
    for (int s2 = 0; s2 < 4; ++s2) {
      const int qb = qb0 + s2 * 16;

      floatx4 st[4];
      __builtin_amdgcn_s_setprio(1);
#pragma unroll
      for (int nt = 0; nt < 4; ++nt) {
        floatx4 z = (floatx4){0.f, 0.f, 0.f, 0.f};
        z = MFMA16(ak[nt][0], aq[s2][0], z);
        z = MFMA16(ak[nt][1], aq[s2][1], z);
        st[nt] = z;
      }
      __builtin_amdgcn_s_setprio(0);

      if (k0 + 63 > qb) {
#pragma unroll
        for (int nt = 0; nt < 4; ++nt)
#pragma unroll
          for (int r = 0; r < 4; ++r)
            if ((k0 + nt * 16 + quad * 4 + r) > (qb + lm)) st[nt][r] = MASKV;
      }

      float a0 = fmaxf(st[0][0], st[0][1]), a1 = fmaxf(st[0][2], st[0][3]);
      float a2 = fmaxf(st[1][0], st[1][1]), a3 = fmaxf(st[1][2], st[1][3]);
      float a4 = fmaxf(st[2][0], st[2][1]), a5 = fmaxf(st[2][2], st[2][3]);
      float a6 = fmaxf(st[3][0], st[3][1]), a7 = fmaxf(st[3][2], st[3][3]);
      float b0 = fmaxf(a0, a1), b1 = fmaxf(a2, a3);
      float b2 = fmaxf(a4, a5), b3 = fmaxf(a6, a7);
      float mx = fmaxf(fmaxf(b0, b1), fmaxf(b2, b3));
      mx = fmaxf(mx, __shfl_xor(mx, 16, 64));
      mx = fmaxf(mx, __shfl_xor(mx, 32, 64));

      if (!__all(mx <= m_i[s2] + 8.0f)) {
        const float mnew = fmaxf(m_i[s2], mx);
        const float alpha = __builtin_amdgcn_exp2f(m_i[s2] - mnew);
        m_i[s2] = mnew;
        l_i[s2] *= alpha;
#pragma unroll
        for (int dn = 0; dn < 4; ++dn) oacc[s2][dn] *= alpha;
      }

#pragma unroll
      for (int nt = 0; nt < 4; ++nt)
#pragma unroll
        for (int r = 0; r < 4; ++r)
          st[nt][r] = __builtin_amdgcn_exp2f(st[nt][r] - m_i[s2]);

      {
        BF16* pws = Ps[w][s2];
#pragma unroll
        for (int nt = 0; nt < 4; ++nt) {
          union { ushort4 u4; ushort u[4]; } pk;
#pragma unroll
          for (int r = 0; r < 4; ++r) {
            BF16 h = __float2bfloat16(st[nt][r]);
            pk.u[r] = *(const ushort*)&h;
          }
          const int g = ((nt * 2 + (quad >> 1)) + lm) & 7;
          *(ushort4*)(pws + lm * 64 + g * 8 + (quad & 1) * 4) = pk.u4;
        }
      }

      if (s2 > 0) {
        const int sp = s2 - 1;
        const BF16* pwp = Ps[w][sp];
        const bhalf8 ap0 = *(const bhalf8*)(pwp + lm * 64 + ((quad + lm) & 7) * 8);
        const bhalf8 ap1 = *(const bhalf8*)(pwp + lm * 64 + ((4 + quad + lm) & 7) * 8);
        __builtin_amdgcn_s_setprio(1);
        floatx4 zl = (floatx4){0.f, 0.f, 0.f, 0.f};
        zl = MFMA16(ones8, ap0, zl);
        zl = MFMA16(ones8, ap1, zl);
#pragma unroll
        for (int dn = 0; dn < 4; ++dn) {
          oacc[sp][dn] = MFMA16(av[dn][0], ap0, oacc[sp][dn]);
          oacc[sp][dn] = MFMA16(av[dn][1], ap1, oacc[sp][dn]);
        }
        __builtin_amdgcn_s_setprio(0);
        l_i[sp] += zl[0];
      }
    }

    {
      const BF16* pwp = Ps[w][3];
      const bhalf8 ap0 = *(const bhalf8*)(pwp + lm * 64 + ((quad + lm) & 7) * 8);
      const bhalf8 ap1 = *(const bhalf8*)(pwp + lm * 64 + ((4 + quad + lm) & 7) * 8);
      __builtin_amdgcn_s_setprio(1);
      floatx4 zl = (floatx4){0.f, 0.f, 0.f, 0.f};
      zl = MFMA16(ones8, ap0, zl);
      zl = MFMA16(ones8, ap1, zl);
#pragma unroll
      for (int dn = 0; dn < 4; ++dn) {
        oacc[3][dn] = MFMA16(av[dn][0], ap0, oacc[3][dn]);
        oacc[3][dn] = MFMA16(av[dn][1], ap1, oacc[3][dn]);
      }
      __builtin_amdgcn_s_setprio(0);
      l_i[3] += zl[0];
    }
  }

  const int b = bh >> 4, h = bh & 15;
#pragma unroll
  for (int s2 = 0; s2 < 4; ++s2) {
    const float inv_l = 1.0f / l_i[s2];
    const size_t orow = (size_t)(b * 2048 + qb0 + s2 * 16 + lm) * 1024 + h * 64;
#pragma unroll
    for (int dn = 0; dn < 4; ++dn) {
      union { ushort4 u4; ushort u[4]; } pk;
#pragma unroll
      for (int r = 0; r < 4; ++r) {
        BF16 h2 = __float2bfloat16(oacc[s2][dn][r] * inv_l);
        pk.u[r] = *(const ushort*)&h2;
      }
      *(ushort4*)(O + orow + dn * 16 + quad * 4) = pk.u4;
    }
  }
}

// ---------------------------------------------------------------------------
extern "C" void kernel_launch(void* const* d_in, const int* in_sizes, int n_in,
                              void* d_out, int out_size, void* d_ws, size_t ws_size,
                              hipStream_t stream) {
  const float* x = (const float*)d_in[0];      // (8192, 1024) f32
  const float* w_qkv = (const float*)d_in[1];  // (1024, 3072) f32
  const float* b_qkv = (const float*)d_in[2];  // (3072) f32
  const float* w_fc = (const float*)d_in[3];   // (1024, 1024) f32
  const float* b_fc = (const float*)d_in[4];   // (1024) f32
  float* out = (float*)d_out;                  // (8192, 1024) f32

  BF16* ws = (BF16*)d_ws;
  BF16* wTqkv = ws;                    // 3072*1024 bf16
  BF16* wTfc = wTqkv + 3072 * 1024;    // 1024*1024
  BF16* xb = wTfc + 1024 * 1024;       // 8192*1024 bf16
  BF16* Qb = xb + 8388608;             // (B,H,S,64)  pre-scaled by QSCALE
  BF16* Kb = Qb + 8388608;             // (B,H,S,64)
  BF16* VTb = Kb + 8388608;            // (B,H,64,S)
  BF16* Ob = VTb + 8388608;            // (B*S, 1024)
  // total ~92 MB of d_ws

  cvt_f32_bf16<<<4096, 256, 0, stream>>>(x, xb);
  transpose_cvt<<<dim3(96, 32), dim3(32, 8), 0, stream>>>(w_qkv, (ushort*)wTqkv, 1024, 3072);
  transpose_cvt<<<dim3(32, 32), dim3(32, 8), 0, stream>>>(w_fc, (ushort*)wTfc, 1024, 1024);

  gemm_qkv256<<<dim3(12, 32), 512, 0, stream>>>(xb, wTqkv, b_qkv, Qb, Kb, VTb, 1024);
  flash_attn<<<dim3(512), 256, 0, stream>>>(Qb, Kb, VTb, Ob);
  gemm_bt<0><<<dim3(8, 64), 256, 0, stream>>>(
      Ob, wTfc, b_fc, (void*)out, nullptr, nullptr, 8192, 1024, 1024);
}

// Round 12
// 270.532 us; speedup vs baseline: 1.1241x; 1.1241x over previous
//
#include <hip/hip_runtime.h>
#include <hip/hip_bf16.h>
#include <cstdint>

#define BF16 __hip_bfloat16

typedef __attribute__((ext_vector_type(8))) short bhalf8;   // 8 bf16 (4 VGPRs)
typedef __attribute__((ext_vector_type(4))) float floatx4;  // 4 fp32 acc

#define MFMA16(a, b, c) __builtin_amdgcn_mfma_f32_16x16x32_bf16((a), (b), (c), 0, 0, 0)

#define MASKV (-30000.0f)
#define QSCALE 0.18033688011112042f  // 0.125 * log2(e); folded into Q

__device__ __forceinline__ bhalf8 cvt8(const float* p) {
  const float4 f0 = *(const float4*)p;
  const float4 f1 = *(const float4*)(p + 4);
  union { bhalf8 v; ushort u[8]; } r;
  const float t[8] = {f0.x, f0.y, f0.z, f0.w, f1.x, f1.y, f1.z, f1.w};
#pragma unroll
  for (int i = 0; i < 8; ++i) {
    BF16 h = __float2bfloat16(t[i]);
    r.u[i] = *(const ushort*)&h;
  }
  return r.v;
}

// ---------------------------------------------------------------------------
// Bulk f32 -> bf16 convert, 8 elems/thread.
// ---------------------------------------------------------------------------
__global__ void cvt_f32_bf16(const float* __restrict__ in, BF16* __restrict__ out) {
  const size_t i = ((size_t)blockIdx.x * 256 + threadIdx.x) * 8;
  *(bhalf8*)(out + i) = cvt8(in + i);
}

// ---------------------------------------------------------------------------
// Transpose+convert, both weight matrices in ONE dispatch.
// blockIdx.x < 96: w_qkv (1024 x 3072); else: w_fc (1024 x 1024).
// Block (32,8), LDS 32x33 pad (R4-proven inner loop).
// ---------------------------------------------------------------------------
__global__ void transpose_cvt2(const float* __restrict__ in0, ushort* __restrict__ out0,
                               const float* __restrict__ in1, ushort* __restrict__ out1) {
  __shared__ ushort t[32][33];
  const bool second = blockIdx.x >= 96;
  const float* in = second ? in1 : in0;
  ushort* out = second ? out1 : out0;
  const int C = second ? 1024 : 3072;
  const int R = 1024;
  const int bx = second ? (blockIdx.x - 96) : blockIdx.x;
  const int c0 = bx * 32, r0 = blockIdx.y * 32;
  const int tx = threadIdx.x, ty = threadIdx.y;
#pragma unroll
  for (int j = 0; j < 32; j += 8) {
    BF16 h = __float2bfloat16(in[(size_t)(r0 + ty + j) * C + c0 + tx]);
    t[ty + j][tx] = *(const ushort*)&h;
  }
  __syncthreads();
#pragma unroll
  for (int j = 0; j < 32; j += 8)
    out[(size_t)(c0 + ty + j) * R + r0 + tx] = t[tx][ty + j];
}

// ---------------------------------------------------------------------------
// GEMM C = A(MxK,bf16) * Bt(NxK,bf16)^T + bias(f32), fp32 accum.
// 128x128 tile, BK=64, 4 waves (2x2 of 64x64), 16x16x32 MFMA.
// EXACT R4 configuration (best measured total, 272.6 us): plain blockIdx
// tiling (no swizzle — never showed a measured win here), (256,2),
// register-prefetch staging. R10/R11's 256-tile ring pipeline measured
// SLOWER at this shape (101 us vs <=100; K=1024 too shallow, 1 block/CU
// tail) — reverted.
// MODE 0: float out, C0f[m*Nd + n] = v + bias[n]
// MODE 1: bf16 QKV scatter: n->(which,h,d); Q (x QSCALE)/K as (B,H,S,64),
//         V^T as (B,H,64,S)
// ---------------------------------------------------------------------------
template <int MODE>
__global__ __launch_bounds__(256, 2) void gemm_bt(
    const BF16* __restrict__ A, const BF16* __restrict__ Bt, const float* __restrict__ bias,
    void* __restrict__ C0v, BF16* __restrict__ C1, BF16* __restrict__ C2,
    int Md, int Nd, int Kd) {
  __shared__ __align__(16) BF16 As[128 * 64];
  __shared__ __align__(16) BF16 Bs[128 * 64];

  const int tid = threadIdx.x;
  const int w = tid >> 6, lane = tid & 63;
  const int lm = lane & 15, quad = lane >> 4;
  const int wm = (w >> 1) * 64, wn = (w & 1) * 64;
  const int tile_m = blockIdx.y * 128, tile_n = blockIdx.x * 128;

  floatx4 acc[4][4];
#pragma unroll
  for (int i = 0; i < 4; ++i)
#pragma unroll
    for (int j = 0; j < 4; ++j) acc[i][j] = (floatx4){0.f, 0.f, 0.f, 0.f};

  int srow[4], sgs[4], sslot[4];
#pragma unroll
  for (int j = 0; j < 4; ++j) {
    const int slot = (j * 4 + w) * 64 + lane;
    sslot[j] = slot;
    srow[j] = slot >> 3;
    sgs[j] = ((slot & 7) - (slot >> 3)) & 7;
  }

  bhalf8 va[4], vb[4], nva[4], nvb[4];
#pragma unroll
  for (int j = 0; j < 4; ++j) {
    va[j] = *(const bhalf8*)(A + (size_t)(tile_m + srow[j]) * Kd + sgs[j] * 8);
    vb[j] = *(const bhalf8*)(Bt + (size_t)(tile_n + srow[j]) * Kd + sgs[j] * 8);
  }

  for (int k0 = 0; k0 < Kd; k0 += 64) {
    __syncthreads();  // previous iter's LDS reads complete
#pragma unroll
    for (int j = 0; j < 4; ++j) {
      *(bhalf8*)(As + sslot[j] * 8) = va[j];
      *(bhalf8*)(Bs + sslot[j] * 8) = vb[j];
    }
    __syncthreads();

    if (k0 + 64 < Kd) {  // prefetch next K-tile; latency overlaps compute below
      const int k1 = k0 + 64;
#pragma unroll
      for (int j = 0; j < 4; ++j) {
        nva[j] = *(const bhalf8*)(A + (size_t)(tile_m + srow[j]) * Kd + k1 + sgs[j] * 8);
        nvb[j] = *(const bhalf8*)(Bt + (size_t)(tile_n + srow[j]) * Kd + k1 + sgs[j] * 8);
      }
    }

#pragma unroll
    for (int s = 0; s < 2; ++s) {
      bhalf8 af[4], bfr[4];
#pragma unroll
      for (int mt = 0; mt < 4; ++mt) {
        const int r = wm + mt * 16 + lm;
        const int g = ((s * 4 + quad) + r) & 7;
        af[mt] = *(const bhalf8*)(As + r * 64 + g * 8);
      }
#pragma unroll
      for (int nt = 0; nt < 4; ++nt) {
        const int r = wn + nt * 16 + lm;
        const int g = ((s * 4 + quad) + r) & 7;
        bfr[nt] = *(const bhalf8*)(Bs + r * 64 + g * 8);
      }
#pragma unroll
      for (int mt = 0; mt < 4; ++mt)
#pragma unroll
        for (int nt = 0; nt < 4; ++nt)
          acc[mt][nt] = MFMA16(af[mt], bfr[nt], acc[mt][nt]);
    }
#pragma unroll
    for (int j = 0; j < 4; ++j) { va[j] = nva[j]; vb[j] = nvb[j]; }
  }

  // Epilogue. C layout: col = lane&15, row = quad*4 + reg (m89/m91).
#pragma unroll
  for (int nt = 0; nt < 4; ++nt) {
    const int n = tile_n + wn + nt * 16 + lm;
    const float bv = bias[n];
#pragma unroll
    for (int mt = 0; mt < 4; ++mt) {
      const int m0 = tile_m + wm + mt * 16 + quad * 4;
      floatx4 v = acc[mt][nt];
      if (MODE == 0) {
        float* C0f = (float*)C0v;
#pragma unroll
        for (int r = 0; r < 4; ++r)
          C0f[(size_t)(m0 + r) * Nd + n] = v[r] + bv;
      } else {
        const int which = n >> 10;
        const int h = (n >> 6) & 15;
        const int d = n & 63;
        if (which == 2) {
          // V^T: 4 regs = 4 consecutive s at fixed d -> one 8 B store
          const int b = m0 >> 11, s0 = m0 & 2047;
          union { ushort4 u4; ushort u[4]; } pk;
#pragma unroll
          for (int r = 0; r < 4; ++r) {
            BF16 hv = __float2bfloat16(v[r] + bv);
            pk.u[r] = *(const ushort*)&hv;
          }
          *(ushort4*)(C2 + ((size_t)((b * 16 + h) * 64 + d)) * 2048 + s0) = pk.u4;
        } else {
          BF16* dst = (which == 0) ? (BF16*)C0v : C1;
          const float sc = (which == 0) ? QSCALE : 1.0f;  // fold softmax scale into Q
#pragma unroll
          for (int r = 0; r < 4; ++r) {
            const int m = m0 + r, b = m >> 11, si = m & 2047;
            dst[((size_t)(b * 16 + h) * 2048 + si) * 64 + d] =
                __float2bfloat16((v[r] + bv) * sc);
          }
        }
      }
    }
  }
}

// ---------------------------------------------------------------------------
// Causal flash attention — R9 version verbatim (97.6 us, best measured):
// MFMA row-sum for l (2 ones-MFMAs replace the 16-op serial add + 2
// shuffles), pairwise max tree, lagged PV, defer-max, chunk rotation,
// XCD-bijective grid, (256,2)/116-VGPR no-spill envelope.
// ---------------------------------------------------------------------------
__global__ __launch_bounds__(256, 2) void flash_attn(
    const BF16* __restrict__ Q, const BF16* __restrict__ Kmat,
    const BF16* __restrict__ VT, BF16* __restrict__ O) {
  __shared__ __align__(16) BF16 Ps[4][4][16 * 64];  // [wave][set] = 32 KB

  const int tid = threadIdx.x;
  const int w = tid >> 6, lane = tid & 63;
  const int lm = lane & 15, quad = lane >> 4;

  const int bid = blockIdx.x;
  const int xcd = bid & 7;
  const int li = bid >> 3;
  const int bh = xcd * 8 + (li >> 3);
  const int x = li & 7;

  const int sel = (w + x) & 3;
  const int qt = (sel == 0) ? x : (sel == 1) ? (15 - x) : (sel == 2) ? (16 + x) : (31 - x);
  const int qb0 = qt * 64;
  const size_t bh_off = (size_t)bh * (2048 * 64);

  union { bhalf8 v; ushort u[8]; } onesu;
#pragma unroll
  for (int i = 0; i < 8; ++i) onesu.u[i] = 0x3F80;  // bf16 1.0
  const bhalf8 ones8 = onesu.v;

  bhalf8 aq[4][2];
#pragma unroll
  for (int s2 = 0; s2 < 4; ++s2) {
    const BF16* qp = Q + bh_off + (size_t)(qb0 + s2 * 16 + lm) * 64 + quad * 8;
    aq[s2][0] = *(const bhalf8*)qp;
    aq[s2][1] = *(const bhalf8*)(qp + 32);
  }

  floatx4 oacc[4][4];
  float m_i[4], l_i[4];
#pragma unroll
  for (int s2 = 0; s2 < 4; ++s2) {
    m_i[s2] = MASKV;
    l_i[s2] = 0.f;
#pragma unroll
    for (int i = 0; i < 4; ++i) oacc[s2][i] = (floatx4){0.f, 0.f, 0.f, 0.f};
  }

  for (int kt = 0; kt <= qt; ++kt) {
    const int k0 = kt * 64;

    bhalf8 ak[4][2], av[4][2];
#pragma unroll
    for (int nt = 0; nt < 4; ++nt) {
      const BF16* kp = Kmat + bh_off + (size_t)(k0 + nt * 16 + lm) * 64 + quad * 8;
      ak[nt][0] = *(const bhalf8*)kp;
      ak[nt][1] = *(const bhalf8*)(kp + 32);
      const BF16* vp = VT + bh_off + (size_t)(nt * 16 + lm) * 2048 + k0 + quad * 8;
      av[nt][0] = *(const bhalf8*)vp;
      av[nt][1] = *(const bhalf8*)(vp + 32);
    }

#pragma unroll
    for (int s2 = 0; s2 < 4; ++s2) {
      const int qb = qb0 + s2 * 16;

      floatx4 st[4];
      __builtin_amdgcn_s_setprio(1);
#pragma unroll
      for (int nt = 0; nt < 4; ++nt) {
        floatx4 z = (floatx4){0.f, 0.f, 0.f, 0.f};
        z = MFMA16(ak[nt][0], aq[s2][0], z);
        z = MFMA16(ak[nt][1], aq[s2][1], z);
        st[nt] = z;
      }
      __builtin_amdgcn_s_setprio(0);

      if (k0 + 63 > qb) {
#pragma unroll
        for (int nt = 0; nt < 4; ++nt)
#pragma unroll
          for (int r = 0; r < 4; ++r)
            if ((k0 + nt * 16 + quad * 4 + r) > (qb + lm)) st[nt][r] = MASKV;
      }

      float a0 = fmaxf(st[0][0], st[0][1]), a1 = fmaxf(st[0][2], st[0][3]);
      float a2 = fmaxf(st[1][0], st[1][1]), a3 = fmaxf(st[1][2], st[1][3]);
      float a4 = fmaxf(st[2][0], st[2][1]), a5 = fmaxf(st[2][2], st[2][3]);
      float a6 = fmaxf(st[3][0], st[3][1]), a7 = fmaxf(st[3][2], st[3][3]);
      float b0 = fmaxf(a0, a1), b1 = fmaxf(a2, a3);
      float b2 = fmaxf(a4, a5), b3 = fmaxf(a6, a7);
      float mx = fmaxf(fmaxf(b0, b1), fmaxf(b2, b3));
      mx = fmaxf(mx, __shfl_xor(mx, 16, 64));
      mx = fmaxf(mx, __shfl_xor(mx, 32, 64));

      if (!__all(mx <= m_i[s2] + 8.0f)) {
        const float mnew = fmaxf(m_i[s2], mx);
        const float alpha = __builtin_amdgcn_exp2f(m_i[s2] - mnew);
        m_i[s2] = mnew;
        l_i[s2] *= alpha;
#pragma unroll
        for (int dn = 0; dn < 4; ++dn) oacc[s2][dn] *= alpha;
      }

#pragma unroll
      for (int nt = 0; nt < 4; ++nt)
#pragma unroll
        for (int r = 0; r < 4; ++r)
          st[nt][r] = __builtin_amdgcn_exp2f(st[nt][r] - m_i[s2]);

      {
        BF16* pws = Ps[w][s2];
#pragma unroll
        for (int nt = 0; nt < 4; ++nt) {
          union { ushort4 u4; ushort u[4]; } pk;
#pragma unroll
          for (int r = 0; r < 4; ++r) {
            BF16 h = __float2bfloat16(st[nt][r]);
            pk.u[r] = *(const ushort*)&h;
          }
          const int g = ((nt * 2 + (quad >> 1)) + lm) & 7;
          *(ushort4*)(pws + lm * 64 + g * 8 + (quad & 1) * 4) = pk.u4;
        }
      }

      if (s2 > 0) {
        const int sp = s2 - 1;
        const BF16* pwp = Ps[w][sp];
        const bhalf8 ap0 = *(const bhalf8*)(pwp + lm * 64 + ((quad + lm) & 7) * 8);
        const bhalf8 ap1 = *(const bhalf8*)(pwp + lm * 64 + ((4 + quad + lm) & 7) * 8);
        __builtin_amdgcn_s_setprio(1);
        floatx4 zl = (floatx4){0.f, 0.f, 0.f, 0.f};
        zl = MFMA16(ones8, ap0, zl);
        zl = MFMA16(ones8, ap1, zl);
#pragma unroll
        for (int dn = 0; dn < 4; ++dn) {
          oacc[sp][dn] = MFMA16(av[dn][0], ap0, oacc[sp][dn]);
          oacc[sp][dn] = MFMA16(av[dn][1], ap1, oacc[sp][dn]);
        }
        __builtin_amdgcn_s_setprio(0);
        l_i[sp] += zl[0];
      }
    }

    {
      const BF16* pwp = Ps[w][3];
      const bhalf8 ap0 = *(const bhalf8*)(pwp + lm * 64 + ((quad + lm) & 7) * 8);
      const bhalf8 ap1 = *(const bhalf8*)(pwp + lm * 64 + ((4 + quad + lm) & 7) * 8);
      __builtin_amdgcn_s_setprio(1);
      floatx4 zl = (floatx4){0.f, 0.f, 0.f, 0.f};
      zl = MFMA16(ones8, ap0, zl);
      zl = MFMA16(ones8, ap1, zl);
#pragma unroll
      for (int dn = 0; dn < 4; ++dn) {
        oacc[3][dn] = MFMA16(av[dn][0], ap0, oacc[3][dn]);
        oacc[3][dn] = MFMA16(av[dn][1], ap1, oacc[3][dn]);
      }
      __builtin_amdgcn_s_setprio(0);
      l_i[3] += zl[0];
    }
  }

  const int b = bh >> 4, h = bh & 15;
#pragma unroll
  for (int s2 = 0; s2 < 4; ++s2) {
    const float inv_l = 1.0f / l_i[s2];
    const size_t orow = (size_t)(b * 2048 + qb0 + s2 * 16 + lm) * 1024 + h * 64;
#pragma unroll
    for (int dn = 0; dn < 4; ++dn) {
      union { ushort4 u4; ushort u[4]; } pk;
#pragma unroll
      for (int r = 0; r < 4; ++r) {
        BF16 h2 = __float2bfloat16(oacc[s2][dn][r] * inv_l);
        pk.u[r] = *(const ushort*)&h2;
      }
      *(ushort4*)(O + orow + dn * 16 + quad * 4) = pk.u4;
    }
  }
}

// ---------------------------------------------------------------------------
extern "C" void kernel_launch(void* const* d_in, const int* in_sizes, int n_in,
                              void* d_out, int out_size, void* d_ws, size_t ws_size,
                              hipStream_t stream) {
  const float* x = (const float*)d_in[0];      // (8192, 1024) f32
  const float* w_qkv = (const float*)d_in[1];  // (1024, 3072) f32
  const float* b_qkv = (const float*)d_in[2];  // (3072) f32
  const float* w_fc = (const float*)d_in[3];   // (1024, 1024) f32
  const float* b_fc = (const float*)d_in[4];   // (1024) f32
  float* out = (float*)d_out;                  // (8192, 1024) f32

  BF16* ws = (BF16*)d_ws;
  BF16* wTqkv = ws;                    // 3072*1024 bf16
  BF16* wTfc = wTqkv + 3072 * 1024;    // 1024*1024
  BF16* xb = wTfc + 1024 * 1024;       // 8192*1024 bf16
  BF16* Qb = xb + 8388608;             // (B,H,S,64)  pre-scaled by QSCALE
  BF16* Kb = Qb + 8388608;             // (B,H,S,64)
  BF16* VTb = Kb + 8388608;            // (B,H,64,S)
  BF16* Ob = VTb + 8388608;            // (B*S, 1024)
  // total ~92 MB of d_ws

  cvt_f32_bf16<<<4096, 256, 0, stream>>>(x, xb);
  transpose_cvt2<<<dim3(128, 32), dim3(32, 8), 0, stream>>>(
      w_qkv, (ushort*)wTqkv, w_fc, (ushort*)wTfc);

  gemm_bt<1><<<dim3(24, 64), 256, 0, stream>>>(
      xb, wTqkv, b_qkv, (void*)Qb, Kb, VTb, 8192, 3072, 1024);
  flash_attn<<<dim3(512), 256, 0, stream>>>(Qb, Kb, VTb, Ob);
  gemm_bt<0><<<dim3(8, 64), 256, 0, stream>>>(
      Ob, wTfc, b_fc, (void*)out, nullptr, nullptr, 8192, 1024, 1024);
}